// Round 8
// baseline (365.682 us; speedup 1.0000x reference)
//
#include <hip/hip_runtime.h>

// ---------------------------------------------------------------------------
// LRU single step, fused — v9 (fused phases: y-GEMM(s) ∥ GEMM-A(s+1)).
//   state = Lambda * x0 + Bn @ u              (complex; stored PLANAR re|im)
//   y     = s_re @ C_re^T - s_im @ C_im^T + u @ D^T
//
// Ladder (lru_main dur / FETCH+WRITE MB):
//  v2 192/196 baseline. v3 247/344 fragment global I/O BAD. v4 268/426
//  window>L3 BAD. v5/v6 ~224/505 window BAD (nt-store theory falsified).
//  v7 195/196 dbuf+prefetch NULL. v8 200/241 rolling reg pipe NULL
//  (compiler re-folds; VGPR stayed 64).
// v9 diagnosis: phase COUNT x phase LATENCY is the floor. 15 serial phases
//  per block, each ends in a vmcnt(0)-draining barrier; 2 barrier-groups/CU
//  can't tile that. Fix: GEMM-A(s+1) depends only on Xu -> fuse it with
//  y-GEMM(s) (different Sc buffers). 9 GEMM phases -> 5; fused phase has 2
//  independent load->MFMA streams (8 acc chains). x0 prefetch moves to the
//  fused-phase top (full phase of latency cover).
// Kept: ROWS=32, 54.3KB LDS (2 blk/CU residency window), linear global I/O,
//  swapped-operand MFMA, in-place Sc epilogue, launch_bounds(512,4).
// ---------------------------------------------------------------------------

typedef __attribute__((ext_vector_type(8))) short bf16x8;
typedef __attribute__((ext_vector_type(4))) float f32x4;
typedef unsigned short u16;

#define N_ROWS 32768
#define IN_DIM 256
#define SD 512
#define OUT_DIM 256
#define ROWS 32          // rows (n) per block
#define NTHR 512         // 8 waves
#define TP 264           // tile pitch in u16 (256 + 8 pad)
#define YP 260           // y staging pitch in f32
#define SMEM_U16 27136   // 54,272 B total -> 2 blocks/CU

#define MFMA16(a, b, c) __builtin_amdgcn_mfma_f32_16x16x32_bf16(a, b, c, 0, 0, 0)

__device__ __align__(16) float g_lam[2 * SD];            // lam_re | lam_im
__device__ __align__(16) u16   g_W1[1024 * IN_DIM];      // bf16
__device__ __align__(16) u16   g_Wy[OUT_DIM * 1280];     // bf16

__device__ __forceinline__ u16 f2b(float f) {
    union { float f; unsigned int u; } v; v.f = f;
    unsigned int r = v.u + 0x7FFFu + ((v.u >> 16) & 1u);   // RNE
    return (u16)(r >> 16);
}
__device__ __forceinline__ ushort4 f2b4(f32x4 v) {
    ushort4 b;
    b.x = f2b(v[0]); b.y = f2b(v[1]); b.z = f2b(v[2]); b.w = f2b(v[3]);
    return b;
}
__device__ __forceinline__ f32x4 b2f4(ushort4 b) {
    union { float f; unsigned int u; } t0, t1, t2, t3;
    t0.u = (unsigned)b.x << 16; t1.u = (unsigned)b.y << 16;
    t2.u = (unsigned)b.z << 16; t3.u = (unsigned)b.w << 16;
    return f32x4{t0.f, t1.f, t2.f, t3.f};
}

// --- combined prep (single launch) -----------------------------------------
__global__ void prep_all(const float* __restrict__ nu_log,
                         const float* __restrict__ theta_log,
                         const float* __restrict__ gamma_log,
                         const float* __restrict__ B_re, const float* __restrict__ B_im,
                         const float* __restrict__ C_re, const float* __restrict__ C_im,
                         const float* __restrict__ D) {
    int b = blockIdx.x, t = threadIdx.x;
    if (b < 1024) {
        int w = b & 255;
        int h = (b >> 8) * 128 + (w & 127);
        float g = expf(gamma_log[h]);
        const float* src = (w < 128) ? B_re : B_im;
        g_W1[b * IN_DIM + t] = f2b(src[h * IN_DIM + t] * g);
    } else if (b < 1280) {
        int o = b - 1024;
        #pragma unroll
        for (int it = 0; it < 5; ++it) {
            int c = it * 256 + t;
            float v;
            if (c < 1024) {
                int s = c >> 8, k = c & 255;
                v = (k < 128) ? C_re[o * SD + s * 128 + k]
                              : -C_im[o * SD + s * 128 + (k - 128)];
            } else {
                v = D[o * IN_DIM + (c - 1024)];
            }
            g_Wy[(size_t)o * 1280 + c] = f2b(v);
        }
    } else {
        int h = (b - 1280) * 256 + t;          // [0,512)
        float mod = expf(-expf(nu_log[h]));
        float th  = expf(theta_log[h]);
        g_lam[h]      = mod * cosf(th);
        g_lam[SD + h] = mod * sinf(th);
    }
}

// --- main fused kernel ------------------------------------------------------
__global__ __launch_bounds__(NTHR, 4) void lru_main(
    const float* __restrict__ u, const float* __restrict__ x0_re,
    const float* __restrict__ x0_im,
    float* __restrict__ y_out, float* __restrict__ st_out,
    long long st_limit)     // floats available in the state region of d_out
{
    __shared__ __align__(16) u16 SMEM[SMEM_U16];   // 54,272 B -> 2 blk/CU

    u16* Xu  = SMEM;                  // u tile bf16 [32][TP]
    u16* Sc0 = SMEM + ROWS * TP;      // state chunk bf16, ping
    u16* Sc1 = SMEM + 2 * ROWS * TP;  // state chunk bf16, pong

    const int tid  = threadIdx.x;
    const int wv   = tid >> 6;          // [0,8)
    const int lane = tid & 63;
    const int quad = lane >> 4;
    const int l16  = lane & 15;
    const int kq   = quad * 8;
    const size_t n0 = (size_t)blockIdx.x * ROWS;

    const int Mb = wv * 32;             // wave's M base within a 256-col chunk

    // linear epilogue / prefetch mapping: 1024 slots (32 rows x 32 j4)
    int en[2], ej[2];
    #pragma unroll
    for (int it = 0; it < 2; ++it) {
        int flat = it * NTHR + tid;
        en[it] = flat >> 5; ej[it] = flat & 31;
    }

    // prefetch x0 chunk 0 (overlaps u staging + barrier + GEMM-A(0))
    f32x4 xr[2], xi[2];
    #pragma unroll
    for (int it = 0; it < 2; ++it) {
        size_t roff = (n0 + en[it]) * SD + ej[it] * 4;
        xr[it] = *(const f32x4*)(x0_re + roff);
        xi[it] = *(const f32x4*)(x0_im + roff);
    }

    // stage u tile -> bf16 LDS (32x256, linear f32x4 loads)
    #pragma unroll
    for (int i = 0; i < 4; ++i) {
        int it = tid + i * NTHR;              // 2048 items
        int r = it >> 6, c4 = it & 63;
        f32x4 v = ((const f32x4*)(u + (n0 + r) * IN_DIM))[c4];
        *(ushort4*)(&Xu[r * TP + c4 * 4]) = f2b4(v);
    }
    __syncthreads();

    // epilogue: in-place Sc update (chunk c) + contiguous f32 state stores
    auto epi = [&](u16* Sc, int c) {
        #pragma unroll
        for (int it = 0; it < 2; ++it) {
            const int n = en[it], j = ej[it];
            f32x4 br  = b2f4(*(const ushort4*)(&Sc[n * TP + j * 4]));
            f32x4 bi  = b2f4(*(const ushort4*)(&Sc[n * TP + 128 + j * 4]));
            f32x4 lre = *(const f32x4*)(g_lam + c * 128 + j * 4);
            f32x4 lim = *(const f32x4*)(g_lam + SD + c * 128 + j * 4);
            f32x4 sr = lre * xr[it] - lim * xi[it] + br;
            f32x4 si = lre * xi[it] + lim * xr[it] + bi;
            const long long ir = (long long)((n0 + n) * SD + c * 128 + j * 4);
            const long long ii = (long long)N_ROWS * SD + ir;
            if (ir + 3 < st_limit) {
                *(f32x4*)(st_out + ir) = sr;       // cacheable: L3 absorbs
            } else {
                #pragma unroll
                for (int k = 0; k < 4; ++k)
                    if (ir + k < st_limit) st_out[ir + k] = sr[k];
            }
            if (ii + 3 < st_limit) {
                *(f32x4*)(st_out + ii) = si;
            } else {
                #pragma unroll
                for (int k = 0; k < 4; ++k)
                    if (ii + k < st_limit) st_out[ii + k] = si[k];
            }
            *(ushort4*)(&Sc[n * TP + j * 4])       = f2b4(sr);
            *(ushort4*)(&Sc[n * TP + 128 + j * 4]) = f2b4(si);
        }
    };

    f32x4 accy[2][2];
    #pragma unroll
    for (int ot = 0; ot < 2; ++ot)
        #pragma unroll
        for (int nt = 0; nt < 2; ++nt)
            accy[ot][nt] = f32x4{0.f, 0.f, 0.f, 0.f};

    // ---- GEMM-A(0): Sc0 = W1(0) @ Xu^T --------------------------------
    {
        f32x4 accA[2][2];
        #pragma unroll
        for (int ht = 0; ht < 2; ++ht)
            #pragma unroll
            for (int nt = 0; nt < 2; ++nt)
                accA[ht][nt] = f32x4{0.f, 0.f, 0.f, 0.f};
        const u16* w1b = g_W1 + (size_t)(Mb) * IN_DIM;
        #pragma unroll
        for (int kk = 0; kk < 8; ++kk) {
            bf16x8 a[2], b[2];
            #pragma unroll
            for (int ht = 0; ht < 2; ++ht)
                a[ht] = *(const bf16x8*)(w1b + (ht * 16 + l16) * IN_DIM + kk * 32 + kq);
            #pragma unroll
            for (int nt = 0; nt < 2; ++nt)
                b[nt] = *(const bf16x8*)(&Xu[(nt * 16 + l16) * TP + kk * 32 + kq]);
            accA[0][0] = MFMA16(a[0], b[0], accA[0][0]);
            accA[0][1] = MFMA16(a[0], b[1], accA[0][1]);
            accA[1][0] = MFMA16(a[1], b[0], accA[1][0]);
            accA[1][1] = MFMA16(a[1], b[1], accA[1][1]);
        }
        #pragma unroll
        for (int ht = 0; ht < 2; ++ht)
            #pragma unroll
            for (int nt = 0; nt < 2; ++nt) {
                const int n  = nt * 16 + l16;
                const int hM = Mb + ht * 16 + quad * 4;
                *(ushort4*)(&Sc0[n * TP + hM]) = f2b4(accA[ht][nt]);
            }
    }
    __syncthreads();

    epi(Sc0, 0);
    __syncthreads();

    // ---- main loop: fused [ y-GEMM(s) || GEMM-A(s+1) ] then epi(s+1) ----
    for (int s = 0; s < 3; ++s) {
        u16* Scc = (s & 1) ? Sc1 : Sc0;       // chunk s   (state, bf16)
        u16* Scn = (s & 1) ? Sc0 : Sc1;       // chunk s+1 (Bu target)

        // prefetch x0 for epi(s+1): a full GEMM phase of latency cover
        #pragma unroll
        for (int it = 0; it < 2; ++it) {
            size_t roff = (n0 + en[it]) * SD + (s + 1) * 128 + ej[it] * 4;
            xr[it] = *(const f32x4*)(x0_re + roff);
            xi[it] = *(const f32x4*)(x0_im + roff);
        }

        f32x4 accA[2][2];
        #pragma unroll
        for (int ht = 0; ht < 2; ++ht)
            #pragma unroll
            for (int nt = 0; nt < 2; ++nt)
                accA[ht][nt] = f32x4{0.f, 0.f, 0.f, 0.f};
        const u16* w1b = g_W1 + (size_t)((s + 1) * 256 + Mb) * IN_DIM;

        #pragma unroll
        for (int kk = 0; kk < 8; ++kk) {
            bf16x8 aA[2], aY[2], bA[2], bY[2];
            #pragma unroll
            for (int ht = 0; ht < 2; ++ht) {
                aA[ht] = *(const bf16x8*)(w1b + (ht * 16 + l16) * IN_DIM + kk * 32 + kq);
                aY[ht] = *(const bf16x8*)(g_Wy + (size_t)(Mb + ht * 16 + l16) * 1280
                                          + s * 256 + kk * 32 + kq);
            }
            #pragma unroll
            for (int nt = 0; nt < 2; ++nt) {
                bA[nt] = *(const bf16x8*)(&Xu[(nt * 16 + l16) * TP + kk * 32 + kq]);
                bY[nt] = *(const bf16x8*)(&Scc[(nt * 16 + l16) * TP + kk * 32 + kq]);
            }
            // two independent streams: 8 accumulator chains
            accA[0][0] = MFMA16(aA[0], bA[0], accA[0][0]);
            accy[0][0] = MFMA16(aY[0], bY[0], accy[0][0]);
            accA[0][1] = MFMA16(aA[0], bA[1], accA[0][1]);
            accy[0][1] = MFMA16(aY[0], bY[1], accy[0][1]);
            accA[1][0] = MFMA16(aA[1], bA[0], accA[1][0]);
            accy[1][0] = MFMA16(aY[1], bY[0], accy[1][0]);
            accA[1][1] = MFMA16(aA[1], bA[1], accA[1][1]);
            accy[1][1] = MFMA16(aY[1], bY[1], accy[1][1]);
        }
        // fragments -> Scn as bf16 (contiguous ushort4)
        #pragma unroll
        for (int ht = 0; ht < 2; ++ht)
            #pragma unroll
            for (int nt = 0; nt < 2; ++nt) {
                const int n  = nt * 16 + l16;
                const int hM = Mb + ht * 16 + quad * 4;
                *(ushort4*)(&Scn[n * TP + hM]) = f2b4(accA[ht][nt]);
            }
        __syncthreads();            // Scn (Bu bf16) complete; Scc readers done

        epi(Scn, s + 1);
        __syncthreads();            // Scn now bf16 state chunk
    }

    // ---- final fused: y-GEMM(3) from Sc1 || D-GEMM from Xu ---------------
    #pragma unroll
    for (int kk = 0; kk < 8; ++kk) {
        bf16x8 aY[2], aD[2], bY[2], bU[2];
        #pragma unroll
        for (int ht = 0; ht < 2; ++ht) {
            aY[ht] = *(const bf16x8*)(g_Wy + (size_t)(Mb + ht * 16 + l16) * 1280
                                      + 3 * 256 + kk * 32 + kq);
            aD[ht] = *(const bf16x8*)(g_Wy + (size_t)(Mb + ht * 16 + l16) * 1280
                                      + 1024 + kk * 32 + kq);
        }
        #pragma unroll
        for (int nt = 0; nt < 2; ++nt) {
            bY[nt] = *(const bf16x8*)(&Sc1[(nt * 16 + l16) * TP + kk * 32 + kq]);
            bU[nt] = *(const bf16x8*)(&Xu[(nt * 16 + l16) * TP + kk * 32 + kq]);
        }
        accy[0][0] = MFMA16(aY[0], bY[0], accy[0][0]);
        accy[0][1] = MFMA16(aY[0], bY[1], accy[0][1]);
        accy[1][0] = MFMA16(aY[1], bY[0], accy[1][0]);
        accy[1][1] = MFMA16(aY[1], bY[1], accy[1][1]);
        accy[0][0] = MFMA16(aD[0], bU[0], accy[0][0]);
        accy[0][1] = MFMA16(aD[0], bU[1], accy[0][1]);
        accy[1][0] = MFMA16(aD[1], bU[0], accy[1][0]);
        accy[1][1] = MFMA16(aD[1], bU[1], accy[1][1]);
    }

    // ---- y: fragments -> f32 LDS (all tiles dead) -> linear store
    __syncthreads();                // everyone done reading Xu/Sc0/Sc1
    float* Yf = (float*)SMEM;       // [32][YP]  (32*260*4 = 33280 <= 54272)
    #pragma unroll
    for (int ot = 0; ot < 2; ++ot)
        #pragma unroll
        for (int nt = 0; nt < 2; ++nt) {
            const int n   = nt * 16 + l16;
            const int col = Mb + ot * 16 + quad * 4;
            *(f32x4*)(&Yf[n * YP + col]) = accy[ot][nt];
        }
    __syncthreads();
    #pragma unroll
    for (int i = 0; i < 4; ++i) {
        int it = tid + i * NTHR;                  // 2048 items
        int r = it >> 6, c4 = it & 63;
        f32x4 v = *(const f32x4*)(&Yf[r * YP + c4 * 4]);
        *(f32x4*)(y_out + (n0 + r) * OUT_DIM + c4 * 4) = v;
    }
}

extern "C" void kernel_launch(void* const* d_in, const int* in_sizes, int n_in,
                              void* d_out, int out_size, void* d_ws, size_t ws_size,
                              hipStream_t stream) {
    const float* u         = (const float*)d_in[0];
    const float* x0_re     = (const float*)d_in[1];
    const float* x0_im     = (const float*)d_in[2];
    const float* nu_log    = (const float*)d_in[3];
    const float* theta_log = (const float*)d_in[4];
    const float* gamma_log = (const float*)d_in[5];
    const float* B_re      = (const float*)d_in[6];
    const float* B_im      = (const float*)d_in[7];
    const float* C_re      = (const float*)d_in[8];
    const float* C_im      = (const float*)d_in[9];
    const float* D         = (const float*)d_in[10];

    float* y_out  = (float*)d_out;
    float* st_out = y_out + (size_t)N_ROWS * OUT_DIM;
    long long st_limit = (long long)out_size - (long long)N_ROWS * OUT_DIM;

    prep_all<<<1282, 256, 0, stream>>>(nu_log, theta_log, gamma_log,
                                       B_re, B_im, C_re, C_im, D);
    lru_main<<<N_ROWS / ROWS, NTHR, 0, stream>>>(u, x0_re, x0_im,
                                                 y_out, st_out, st_limit);
}

// Round 9
// 353.884 us; speedup vs baseline: 1.0333x; 1.0333x over previous
//
#include <hip/hip_runtime.h>

// ---------------------------------------------------------------------------
// LRU single step, fused — v10 (v7 + nontemporal loads for streams).
//   state = Lambda * x0 + Bn @ u              (complex; stored PLANAR re|im)
//   y     = s_re @ C_re^T - s_im @ C_im^T + u @ D^T
//
// Ladder (lru_main dur / FETCH+WRITE MB):
//  v2 192/196 baseline. v3 247/344 fragment global I/O BAD. v4 268/426
//  residency window>L3 BAD. v5/v6 ~224/505 window BAD (nt-STORE falsified).
//  v7 195/196 BEST: ROWS=32, 54.3KB LDS (2 blk/CU), dbuf Sc.
//  v8 200/241 rolling reg pipe NULL (compiler re-folds).
//  v9 207/241 phase fusion REGRESSED (VGPR-capped, addressing inflation).
// v10 diagnosis: weights (1.15MB/block) should be L2-resident (2.3MB/XCD of
//  4MB), but ~20MB of concurrent streaming data per XCD thrashes L2 -> every
//  weight load is an L3 round-trip (~500cyc) serialized 4-6 deep at VGPR=64.
//  Fix: __builtin_nontemporal_load on the single-use streams (u staging, x0
//  prefetch) -> evict-first in L2 -> weights stay L2-hit. Stores stay plain
//  (v6). Everything else byte-identical to v7.
// ---------------------------------------------------------------------------

typedef __attribute__((ext_vector_type(8))) short bf16x8;
typedef __attribute__((ext_vector_type(4))) float f32x4;
typedef unsigned short u16;

#define N_ROWS 32768
#define IN_DIM 256
#define SD 512
#define OUT_DIM 256
#define ROWS 32          // rows (n) per block
#define NTHR 512         // 8 waves
#define TP 264           // tile pitch in u16 (256 + 8 pad)
#define YP 260           // y staging pitch in f32
#define SMEM_U16 27136   // 54,272 B total -> 2 blocks/CU

#define MFMA16(a, b, c) __builtin_amdgcn_mfma_f32_16x16x32_bf16(a, b, c, 0, 0, 0)

__device__ __align__(16) float g_lam[2 * SD];            // lam_re | lam_im
__device__ __align__(16) u16   g_W1[1024 * IN_DIM];      // bf16
__device__ __align__(16) u16   g_Wy[OUT_DIM * 1280];     // bf16

__device__ __forceinline__ u16 f2b(float f) {
    union { float f; unsigned int u; } v; v.f = f;
    unsigned int r = v.u + 0x7FFFu + ((v.u >> 16) & 1u);   // RNE
    return (u16)(r >> 16);
}
__device__ __forceinline__ ushort4 f2b4(f32x4 v) {
    ushort4 b;
    b.x = f2b(v[0]); b.y = f2b(v[1]); b.z = f2b(v[2]); b.w = f2b(v[3]);
    return b;
}
__device__ __forceinline__ f32x4 b2f4(ushort4 b) {
    union { float f; unsigned int u; } t0, t1, t2, t3;
    t0.u = (unsigned)b.x << 16; t1.u = (unsigned)b.y << 16;
    t2.u = (unsigned)b.z << 16; t3.u = (unsigned)b.w << 16;
    return f32x4{t0.f, t1.f, t2.f, t3.f};
}

// --- combined prep (single launch) -----------------------------------------
__global__ void prep_all(const float* __restrict__ nu_log,
                         const float* __restrict__ theta_log,
                         const float* __restrict__ gamma_log,
                         const float* __restrict__ B_re, const float* __restrict__ B_im,
                         const float* __restrict__ C_re, const float* __restrict__ C_im,
                         const float* __restrict__ D) {
    int b = blockIdx.x, t = threadIdx.x;
    if (b < 1024) {
        int w = b & 255;
        int h = (b >> 8) * 128 + (w & 127);
        float g = expf(gamma_log[h]);
        const float* src = (w < 128) ? B_re : B_im;
        g_W1[b * IN_DIM + t] = f2b(src[h * IN_DIM + t] * g);
    } else if (b < 1280) {
        int o = b - 1024;
        #pragma unroll
        for (int it = 0; it < 5; ++it) {
            int c = it * 256 + t;
            float v;
            if (c < 1024) {
                int s = c >> 8, k = c & 255;
                v = (k < 128) ? C_re[o * SD + s * 128 + k]
                              : -C_im[o * SD + s * 128 + (k - 128)];
            } else {
                v = D[o * IN_DIM + (c - 1024)];
            }
            g_Wy[(size_t)o * 1280 + c] = f2b(v);
        }
    } else {
        int h = (b - 1280) * 256 + t;          // [0,512)
        float mod = expf(-expf(nu_log[h]));
        float th  = expf(theta_log[h]);
        g_lam[h]      = mod * cosf(th);
        g_lam[SD + h] = mod * sinf(th);
    }
}

// --- main fused kernel ------------------------------------------------------
__global__ __launch_bounds__(NTHR, 4) void lru_main(
    const float* __restrict__ u, const float* __restrict__ x0_re,
    const float* __restrict__ x0_im,
    float* __restrict__ y_out, float* __restrict__ st_out,
    long long st_limit)     // floats available in the state region of d_out
{
    __shared__ __align__(16) u16 SMEM[SMEM_U16];   // 54,272 B -> 2 blk/CU

    u16* Xu  = SMEM;                  // u tile bf16 [32][TP]
    u16* Sc0 = SMEM + ROWS * TP;      // state chunk bf16, ping
    u16* Sc1 = SMEM + 2 * ROWS * TP;  // state chunk bf16, pong

    const int tid  = threadIdx.x;
    const int wv   = tid >> 6;          // [0,8)
    const int lane = tid & 63;
    const int quad = lane >> 4;
    const int l16  = lane & 15;
    const int kq   = quad * 8;
    const size_t n0 = (size_t)blockIdx.x * ROWS;

    const int Mb = wv * 32;             // wave's M base within a 256-col chunk

    // linear epilogue / prefetch mapping: 1024 slots (32 rows x 32 j4)
    int en[2], ej[2];
    #pragma unroll
    for (int it = 0; it < 2; ++it) {
        int flat = it * NTHR + tid;
        en[it] = flat >> 5; ej[it] = flat & 31;
    }

    // prefetch x0 chunk 0 (nt: evict-first, don't thrash weight lines)
    f32x4 xr[2], xi[2];
    #pragma unroll
    for (int it = 0; it < 2; ++it) {
        size_t roff = (n0 + en[it]) * SD + ej[it] * 4;
        xr[it] = __builtin_nontemporal_load((const f32x4*)(x0_re + roff));
        xi[it] = __builtin_nontemporal_load((const f32x4*)(x0_im + roff));
    }

    // stage u tile -> bf16 LDS (32x256, linear nt f32x4 loads)
    #pragma unroll
    for (int i = 0; i < 4; ++i) {
        int it = tid + i * NTHR;              // 2048 items
        int r = it >> 6, c4 = it & 63;
        f32x4 v = __builtin_nontemporal_load(
            (const f32x4*)(u + (n0 + r) * IN_DIM) + c4);
        *(ushort4*)(&Xu[r * TP + c4 * 4]) = f2b4(v);
    }
    __syncthreads();

    f32x4 accy[2][2];
    #pragma unroll
    for (int ot = 0; ot < 2; ++ot)
        #pragma unroll
        for (int nt = 0; nt < 2; ++nt)
            accy[ot][nt] = f32x4{0.f, 0.f, 0.f, 0.f};

    for (int s = 0; s < 4; ++s) {
        u16* Sc = (s & 1) ? Sc1 : Sc0;        // double buffer

        // ---- GEMM-A (swapped): Bu[M=256(re|im)][n=32] = W1_chunk @ Xu^T
        f32x4 acc[2][2];
        #pragma unroll
        for (int ht = 0; ht < 2; ++ht)
            #pragma unroll
            for (int nt = 0; nt < 2; ++nt)
                acc[ht][nt] = f32x4{0.f, 0.f, 0.f, 0.f};
        const u16* w1b = g_W1 + (size_t)(s * 256 + Mb) * IN_DIM;
        #pragma unroll
        for (int k0 = 0; k0 < IN_DIM; k0 += 32) {
            bf16x8 a[2], b[2];
            #pragma unroll
            for (int ht = 0; ht < 2; ++ht)
                a[ht] = *(const bf16x8*)(w1b + (ht * 16 + l16) * IN_DIM + k0 + kq);
            #pragma unroll
            for (int nt = 0; nt < 2; ++nt)
                b[nt] = *(const bf16x8*)(&Xu[(nt * 16 + l16) * TP + k0 + kq]);
            #pragma unroll
            for (int ht = 0; ht < 2; ++ht)
                #pragma unroll
                for (int nt = 0; nt < 2; ++nt)
                    acc[ht][nt] = MFMA16(a[ht], b[nt], acc[ht][nt]);
        }
        // fragments -> Sc as bf16 (contiguous ushort4: lane owns 4 consec h)
        #pragma unroll
        for (int ht = 0; ht < 2; ++ht)
            #pragma unroll
            for (int nt = 0; nt < 2; ++nt) {
                const int n  = nt * 16 + l16;
                const int hM = Mb + ht * 16 + quad * 4;
                *(ushort4*)(&Sc[n * TP + hM]) = f2b4(acc[ht][nt]);
            }
        __syncthreads();            // barrier A: Sc (Bu bf16) complete

        // ---- linear epilogue: in-place Sc update + contiguous f32 stores
        #pragma unroll
        for (int it = 0; it < 2; ++it) {
            const int n = en[it], j = ej[it];
            f32x4 br  = b2f4(*(const ushort4*)(&Sc[n * TP + j * 4]));
            f32x4 bi  = b2f4(*(const ushort4*)(&Sc[n * TP + 128 + j * 4]));
            f32x4 lre = *(const f32x4*)(g_lam + s * 128 + j * 4);
            f32x4 lim = *(const f32x4*)(g_lam + SD + s * 128 + j * 4);
            f32x4 sr = lre * xr[it] - lim * xi[it] + br;
            f32x4 si = lre * xi[it] + lim * xr[it] + bi;
            const long long ir = (long long)((n0 + n) * SD + s * 128 + j * 4);
            const long long ii = (long long)N_ROWS * SD + ir;
            if (ir + 3 < st_limit) {
                *(f32x4*)(st_out + ir) = sr;       // cacheable: L3 absorbs
            } else {
                #pragma unroll
                for (int k = 0; k < 4; ++k)
                    if (ir + k < st_limit) st_out[ir + k] = sr[k];
            }
            if (ii + 3 < st_limit) {
                *(f32x4*)(st_out + ii) = si;
            } else {
                #pragma unroll
                for (int k = 0; k < 4; ++k)
                    if (ii + k < st_limit) st_out[ii + k] = si[k];
            }
            *(ushort4*)(&Sc[n * TP + j * 4])       = f2b4(sr);
            *(ushort4*)(&Sc[n * TP + 128 + j * 4]) = f2b4(si);
        }

        // prefetch x0 for next chunk BEFORE barrier B (nt): latency rides
        // under barrier + y-GEMM + next GEMM-A.
        if (s < 3) {
            #pragma unroll
            for (int it = 0; it < 2; ++it) {
                size_t roff = (n0 + en[it]) * SD + (s + 1) * 128 + ej[it] * 4;
                xr[it] = __builtin_nontemporal_load((const f32x4*)(x0_re + roff));
                xi[it] = __builtin_nontemporal_load((const f32x4*)(x0_im + roff));
            }
        }
        __syncthreads();            // barrier B: Sc now bf16 state chunk

        // ---- partial y-GEMM (swapped): accy += Wy_chunk @ Sc^T
        // (no barrier after: next chunk writes the OTHER Sc buffer)
        #pragma unroll
        for (int k0 = 0; k0 < 256; k0 += 32) {
            bf16x8 a[2], b[2];
            #pragma unroll
            for (int ot = 0; ot < 2; ++ot)
                a[ot] = *(const bf16x8*)(g_Wy + (size_t)(Mb + ot * 16 + l16) * 1280
                                         + s * 256 + k0 + kq);
            #pragma unroll
            for (int nt = 0; nt < 2; ++nt)
                b[nt] = *(const bf16x8*)(&Sc[(nt * 16 + l16) * TP + k0 + kq]);
            #pragma unroll
            for (int ot = 0; ot < 2; ++ot)
                #pragma unroll
                for (int nt = 0; nt < 2; ++nt)
                    accy[ot][nt] = MFMA16(a[ot], b[nt], accy[ot][nt]);
        }
    }

    // ---- y u-part: accy += D @ Xu^T
    #pragma unroll
    for (int k0 = 0; k0 < IN_DIM; k0 += 32) {
        bf16x8 a[2], b[2];
        #pragma unroll
        for (int ot = 0; ot < 2; ++ot)
            a[ot] = *(const bf16x8*)(g_Wy + (size_t)(Mb + ot * 16 + l16) * 1280
                                     + 1024 + k0 + kq);
        #pragma unroll
        for (int nt = 0; nt < 2; ++nt)
            b[nt] = *(const bf16x8*)(&Xu[(nt * 16 + l16) * TP + k0 + kq]);
        #pragma unroll
        for (int ot = 0; ot < 2; ++ot)
            #pragma unroll
            for (int nt = 0; nt < 2; ++nt)
                accy[ot][nt] = MFMA16(a[ot], b[nt], accy[ot][nt]);
    }

    // ---- y: fragments -> f32 LDS (all tiles dead) -> linear store
    __syncthreads();                // everyone done reading Xu/Sc0/Sc1
    float* Yf = (float*)SMEM;       // [32][YP]  (32*260*4 = 33280 <= 54272)
    #pragma unroll
    for (int ot = 0; ot < 2; ++ot)
        #pragma unroll
        for (int nt = 0; nt < 2; ++nt) {
            const int n   = nt * 16 + l16;
            const int col = Mb + ot * 16 + quad * 4;
            *(f32x4*)(&Yf[n * YP + col]) = accy[ot][nt];
        }
    __syncthreads();
    #pragma unroll
    for (int i = 0; i < 4; ++i) {
        int it = tid + i * NTHR;                  // 2048 items
        int r = it >> 6, c4 = it & 63;
        f32x4 v = *(const f32x4*)(&Yf[r * YP + c4 * 4]);
        *(f32x4*)(y_out + (n0 + r) * OUT_DIM + c4 * 4) = v;
    }
}

extern "C" void kernel_launch(void* const* d_in, const int* in_sizes, int n_in,
                              void* d_out, int out_size, void* d_ws, size_t ws_size,
                              hipStream_t stream) {
    const float* u         = (const float*)d_in[0];
    const float* x0_re     = (const float*)d_in[1];
    const float* x0_im     = (const float*)d_in[2];
    const float* nu_log    = (const float*)d_in[3];
    const float* theta_log = (const float*)d_in[4];
    const float* gamma_log = (const float*)d_in[5];
    const float* B_re      = (const float*)d_in[6];
    const float* B_im      = (const float*)d_in[7];
    const float* C_re      = (const float*)d_in[8];
    const float* C_im      = (const float*)d_in[9];
    const float* D         = (const float*)d_in[10];

    float* y_out  = (float*)d_out;
    float* st_out = y_out + (size_t)N_ROWS * OUT_DIM;
    long long st_limit = (long long)out_size - (long long)N_ROWS * OUT_DIM;

    prep_all<<<1282, 256, 0, stream>>>(nu_log, theta_log, gamma_log,
                                       B_re, B_im, C_re, C_im, D);
    lru_main<<<N_ROWS / ROWS, NTHR, 0, stream>>>(u, x0_re, x0_im,
                                                 y_out, st_out, st_limit);
}

// Round 10
// 352.236 us; speedup vs baseline: 1.0382x; 1.0047x over previous
//
#include <hip/hip_runtime.h>

// ---------------------------------------------------------------------------
// LRU single step, fused — v11 (v10 + chunk rotation + setprio desync).
//   state = Lambda * x0 + Bn @ u              (complex; stored PLANAR re|im)
//   y     = s_re @ C_re^T - s_im @ C_im^T + u @ D^T
//
// Ladder (lru_main dur / FETCH+WRITE MB):
//  v2 192/196 baseline. v3 247/344 fragment global I/O BAD. v4 268/426
//  residency window>L3 BAD. v5/v6 ~224/505 window BAD (nt-STORE falsified).
//  v7 195/196: ROWS=32, 54.3KB LDS (2 blk/CU), dbuf Sc.
//  v8 200 reg-pipe NULL. v9 207 phase-fusion REGRESSED.
//  v10 176/189 WIN: nontemporal LOADS on streams (L2 stops thrashing weights).
// v11 diagnosis: MfmaUtil+VALU = 18% issue -> 82% of cycles NO wave issues;
//  ~1 outstanding VMEM/CU average despite 16 waves. The two resident blocks
//  run the identical 15-phase sequence in lockstep (convoy) -> both drain at
//  barriers simultaneously; the assumed cross-block overlap never happens.
//  Fix: (1) chunk rotation s=(t+blockIdx&3)&3 (y-accum is commutative,
//  state chunks independent) -> co-resident blocks sit in different phases;
//  (2) s_setprio(1) around MFMA clusters (T5: pays exactly when wave roles
//  are split, which rotation creates). Everything else identical to v10.
// ---------------------------------------------------------------------------

typedef __attribute__((ext_vector_type(8))) short bf16x8;
typedef __attribute__((ext_vector_type(4))) float f32x4;
typedef unsigned short u16;

#define N_ROWS 32768
#define IN_DIM 256
#define SD 512
#define OUT_DIM 256
#define ROWS 32          // rows (n) per block
#define NTHR 512         // 8 waves
#define TP 264           // tile pitch in u16 (256 + 8 pad)
#define YP 260           // y staging pitch in f32
#define SMEM_U16 27136   // 54,272 B total -> 2 blocks/CU

#define MFMA16(a, b, c) __builtin_amdgcn_mfma_f32_16x16x32_bf16(a, b, c, 0, 0, 0)

__device__ __align__(16) float g_lam[2 * SD];            // lam_re | lam_im
__device__ __align__(16) u16   g_W1[1024 * IN_DIM];      // bf16
__device__ __align__(16) u16   g_Wy[OUT_DIM * 1280];     // bf16

__device__ __forceinline__ u16 f2b(float f) {
    union { float f; unsigned int u; } v; v.f = f;
    unsigned int r = v.u + 0x7FFFu + ((v.u >> 16) & 1u);   // RNE
    return (u16)(r >> 16);
}
__device__ __forceinline__ ushort4 f2b4(f32x4 v) {
    ushort4 b;
    b.x = f2b(v[0]); b.y = f2b(v[1]); b.z = f2b(v[2]); b.w = f2b(v[3]);
    return b;
}
__device__ __forceinline__ f32x4 b2f4(ushort4 b) {
    union { float f; unsigned int u; } t0, t1, t2, t3;
    t0.u = (unsigned)b.x << 16; t1.u = (unsigned)b.y << 16;
    t2.u = (unsigned)b.z << 16; t3.u = (unsigned)b.w << 16;
    return f32x4{t0.f, t1.f, t2.f, t3.f};
}

// --- combined prep (single launch) -----------------------------------------
__global__ void prep_all(const float* __restrict__ nu_log,
                         const float* __restrict__ theta_log,
                         const float* __restrict__ gamma_log,
                         const float* __restrict__ B_re, const float* __restrict__ B_im,
                         const float* __restrict__ C_re, const float* __restrict__ C_im,
                         const float* __restrict__ D) {
    int b = blockIdx.x, t = threadIdx.x;
    if (b < 1024) {
        int w = b & 255;
        int h = (b >> 8) * 128 + (w & 127);
        float g = expf(gamma_log[h]);
        const float* src = (w < 128) ? B_re : B_im;
        g_W1[b * IN_DIM + t] = f2b(src[h * IN_DIM + t] * g);
    } else if (b < 1280) {
        int o = b - 1024;
        #pragma unroll
        for (int it = 0; it < 5; ++it) {
            int c = it * 256 + t;
            float v;
            if (c < 1024) {
                int s = c >> 8, k = c & 255;
                v = (k < 128) ? C_re[o * SD + s * 128 + k]
                              : -C_im[o * SD + s * 128 + (k - 128)];
            } else {
                v = D[o * IN_DIM + (c - 1024)];
            }
            g_Wy[(size_t)o * 1280 + c] = f2b(v);
        }
    } else {
        int h = (b - 1280) * 256 + t;          // [0,512)
        float mod = expf(-expf(nu_log[h]));
        float th  = expf(theta_log[h]);
        g_lam[h]      = mod * cosf(th);
        g_lam[SD + h] = mod * sinf(th);
    }
}

// --- main fused kernel ------------------------------------------------------
__global__ __launch_bounds__(NTHR, 4) void lru_main(
    const float* __restrict__ u, const float* __restrict__ x0_re,
    const float* __restrict__ x0_im,
    float* __restrict__ y_out, float* __restrict__ st_out,
    long long st_limit)     // floats available in the state region of d_out
{
    __shared__ __align__(16) u16 SMEM[SMEM_U16];   // 54,272 B -> 2 blk/CU

    u16* Xu  = SMEM;                  // u tile bf16 [32][TP]
    u16* Sc0 = SMEM + ROWS * TP;      // state chunk bf16, ping
    u16* Sc1 = SMEM + 2 * ROWS * TP;  // state chunk bf16, pong

    const int tid  = threadIdx.x;
    const int wv   = tid >> 6;          // [0,8)
    const int lane = tid & 63;
    const int quad = lane >> 4;
    const int l16  = lane & 15;
    const int kq   = quad * 8;
    const size_t n0 = (size_t)blockIdx.x * ROWS;

    const int Mb    = wv * 32;          // wave's M base within a 256-col chunk
    const int phase = blockIdx.x & 3;   // chunk rotation (convoy desync)

    // linear epilogue / prefetch mapping: 1024 slots (32 rows x 32 j4)
    int en[2], ej[2];
    #pragma unroll
    for (int it = 0; it < 2; ++it) {
        int flat = it * NTHR + tid;
        en[it] = flat >> 5; ej[it] = flat & 31;
    }

    // prefetch x0 for FIRST chunk s=phase (nt: evict-first)
    f32x4 xr[2], xi[2];
    #pragma unroll
    for (int it = 0; it < 2; ++it) {
        size_t roff = (n0 + en[it]) * SD + phase * 128 + ej[it] * 4;
        xr[it] = __builtin_nontemporal_load((const f32x4*)(x0_re + roff));
        xi[it] = __builtin_nontemporal_load((const f32x4*)(x0_im + roff));
    }

    // stage u tile -> bf16 LDS (32x256, linear nt f32x4 loads)
    #pragma unroll
    for (int i = 0; i < 4; ++i) {
        int it = tid + i * NTHR;              // 2048 items
        int r = it >> 6, c4 = it & 63;
        f32x4 v = __builtin_nontemporal_load(
            (const f32x4*)(u + (n0 + r) * IN_DIM) + c4);
        *(ushort4*)(&Xu[r * TP + c4 * 4]) = f2b4(v);
    }
    __syncthreads();

    f32x4 accy[2][2];
    #pragma unroll
    for (int ot = 0; ot < 2; ++ot)
        #pragma unroll
        for (int nt = 0; nt < 2; ++nt)
            accy[ot][nt] = f32x4{0.f, 0.f, 0.f, 0.f};

    for (int t = 0; t < 4; ++t) {
        const int s = (t + phase) & 3;        // rotated chunk index
        u16* Sc = (t & 1) ? Sc1 : Sc0;        // double buffer

        // ---- GEMM-A (swapped): Bu[M=256(re|im)][n=32] = W1_chunk @ Xu^T
        f32x4 acc[2][2];
        #pragma unroll
        for (int ht = 0; ht < 2; ++ht)
            #pragma unroll
            for (int nt = 0; nt < 2; ++nt)
                acc[ht][nt] = f32x4{0.f, 0.f, 0.f, 0.f};
        const u16* w1b = g_W1 + (size_t)(s * 256 + Mb) * IN_DIM;
        __builtin_amdgcn_s_setprio(1);
        #pragma unroll
        for (int k0 = 0; k0 < IN_DIM; k0 += 32) {
            bf16x8 a[2], b[2];
            #pragma unroll
            for (int ht = 0; ht < 2; ++ht)
                a[ht] = *(const bf16x8*)(w1b + (ht * 16 + l16) * IN_DIM + k0 + kq);
            #pragma unroll
            for (int nt = 0; nt < 2; ++nt)
                b[nt] = *(const bf16x8*)(&Xu[(nt * 16 + l16) * TP + k0 + kq]);
            #pragma unroll
            for (int ht = 0; ht < 2; ++ht)
                #pragma unroll
                for (int nt = 0; nt < 2; ++nt)
                    acc[ht][nt] = MFMA16(a[ht], b[nt], acc[ht][nt]);
        }
        __builtin_amdgcn_s_setprio(0);
        // fragments -> Sc as bf16 (contiguous ushort4: lane owns 4 consec h)
        #pragma unroll
        for (int ht = 0; ht < 2; ++ht)
            #pragma unroll
            for (int nt = 0; nt < 2; ++nt) {
                const int n  = nt * 16 + l16;
                const int hM = Mb + ht * 16 + quad * 4;
                *(ushort4*)(&Sc[n * TP + hM]) = f2b4(acc[ht][nt]);
            }
        __syncthreads();            // barrier A: Sc (Bu bf16) complete

        // ---- linear epilogue: in-place Sc update + contiguous f32 stores
        #pragma unroll
        for (int it = 0; it < 2; ++it) {
            const int n = en[it], j = ej[it];
            f32x4 br  = b2f4(*(const ushort4*)(&Sc[n * TP + j * 4]));
            f32x4 bi  = b2f4(*(const ushort4*)(&Sc[n * TP + 128 + j * 4]));
            f32x4 lre = *(const f32x4*)(g_lam + s * 128 + j * 4);
            f32x4 lim = *(const f32x4*)(g_lam + SD + s * 128 + j * 4);
            f32x4 sr = lre * xr[it] - lim * xi[it] + br;
            f32x4 si = lre * xi[it] + lim * xr[it] + bi;
            const long long ir = (long long)((n0 + n) * SD + s * 128 + j * 4);
            const long long ii = (long long)N_ROWS * SD + ir;
            if (ir + 3 < st_limit) {
                *(f32x4*)(st_out + ir) = sr;       // cacheable: L3 absorbs
            } else {
                #pragma unroll
                for (int k = 0; k < 4; ++k)
                    if (ir + k < st_limit) st_out[ir + k] = sr[k];
            }
            if (ii + 3 < st_limit) {
                *(f32x4*)(st_out + ii) = si;
            } else {
                #pragma unroll
                for (int k = 0; k < 4; ++k)
                    if (ii + k < st_limit) st_out[ii + k] = si[k];
            }
            *(ushort4*)(&Sc[n * TP + j * 4])       = f2b4(sr);
            *(ushort4*)(&Sc[n * TP + 128 + j * 4]) = f2b4(si);
        }

        // prefetch x0 for next rotated chunk BEFORE barrier B (nt)
        if (t < 3) {
            const int sn = (t + 1 + phase) & 3;
            #pragma unroll
            for (int it = 0; it < 2; ++it) {
                size_t roff = (n0 + en[it]) * SD + sn * 128 + ej[it] * 4;
                xr[it] = __builtin_nontemporal_load((const f32x4*)(x0_re + roff));
                xi[it] = __builtin_nontemporal_load((const f32x4*)(x0_im + roff));
            }
        }
        __syncthreads();            // barrier B: Sc now bf16 state chunk

        // ---- partial y-GEMM (swapped): accy += Wy_chunk @ Sc^T
        // (no barrier after: next chunk writes the OTHER Sc buffer)
        __builtin_amdgcn_s_setprio(1);
        #pragma unroll
        for (int k0 = 0; k0 < 256; k0 += 32) {
            bf16x8 a[2], b[2];
            #pragma unroll
            for (int ot = 0; ot < 2; ++ot)
                a[ot] = *(const bf16x8*)(g_Wy + (size_t)(Mb + ot * 16 + l16) * 1280
                                         + s * 256 + k0 + kq);
            #pragma unroll
            for (int nt = 0; nt < 2; ++nt)
                b[nt] = *(const bf16x8*)(&Sc[(nt * 16 + l16) * TP + k0 + kq]);
            #pragma unroll
            for (int ot = 0; ot < 2; ++ot)
                #pragma unroll
                for (int nt = 0; nt < 2; ++nt)
                    accy[ot][nt] = MFMA16(a[ot], b[nt], accy[ot][nt]);
        }
        __builtin_amdgcn_s_setprio(0);
    }

    // ---- y u-part: accy += D @ Xu^T
    __builtin_amdgcn_s_setprio(1);
    #pragma unroll
    for (int k0 = 0; k0 < IN_DIM; k0 += 32) {
        bf16x8 a[2], b[2];
        #pragma unroll
        for (int ot = 0; ot < 2; ++ot)
            a[ot] = *(const bf16x8*)(g_Wy + (size_t)(Mb + ot * 16 + l16) * 1280
                                     + 1024 + k0 + kq);
        #pragma unroll
        for (int nt = 0; nt < 2; ++nt)
            b[nt] = *(const bf16x8*)(&Xu[(nt * 16 + l16) * TP + k0 + kq]);
        #pragma unroll
        for (int ot = 0; ot < 2; ++ot)
            #pragma unroll
            for (int nt = 0; nt < 2; ++nt)
                accy[ot][nt] = MFMA16(a[ot], b[nt], accy[ot][nt]);
    }
    __builtin_amdgcn_s_setprio(0);

    // ---- y: fragments -> f32 LDS (all tiles dead) -> linear store
    __syncthreads();                // everyone done reading Xu/Sc0/Sc1
    float* Yf = (float*)SMEM;       // [32][YP]  (32*260*4 = 33280 <= 54272)
    #pragma unroll
    for (int ot = 0; ot < 2; ++ot)
        #pragma unroll
        for (int nt = 0; nt < 2; ++nt) {
            const int n   = nt * 16 + l16;
            const int col = Mb + ot * 16 + quad * 4;
            *(f32x4*)(&Yf[n * YP + col]) = accy[ot][nt];
        }
    __syncthreads();
    #pragma unroll
    for (int i = 0; i < 4; ++i) {
        int it = tid + i * NTHR;                  // 2048 items
        int r = it >> 6, c4 = it & 63;
        f32x4 v = *(const f32x4*)(&Yf[r * YP + c4 * 4]);
        *(f32x4*)(y_out + (n0 + r) * OUT_DIM + c4 * 4) = v;
    }
}

extern "C" void kernel_launch(void* const* d_in, const int* in_sizes, int n_in,
                              void* d_out, int out_size, void* d_ws, size_t ws_size,
                              hipStream_t stream) {
    const float* u         = (const float*)d_in[0];
    const float* x0_re     = (const float*)d_in[1];
    const float* x0_im     = (const float*)d_in[2];
    const float* nu_log    = (const float*)d_in[3];
    const float* theta_log = (const float*)d_in[4];
    const float* gamma_log = (const float*)d_in[5];
    const float* B_re      = (const float*)d_in[6];
    const float* B_im      = (const float*)d_in[7];
    const float* C_re      = (const float*)d_in[8];
    const float* C_im      = (const float*)d_in[9];
    const float* D         = (const float*)d_in[10];

    float* y_out  = (float*)d_out;
    float* st_out = y_out + (size_t)N_ROWS * OUT_DIM;
    long long st_limit = (long long)out_size - (long long)N_ROWS * OUT_DIM;

    prep_all<<<1282, 256, 0, stream>>>(nu_log, theta_log, gamma_log,
                                       B_re, B_im, C_re, C_im, D);
    lru_main<<<N_ROWS / ROWS, NTHR, 0, stream>>>(u, x0_re, x0_im,
                                                 y_out, st_out, st_limit);
}